// Round 6
// baseline (474.577 us; speedup 1.0000x reference)
//
#include <hip/hip_runtime.h>
#include <math.h>

// Problem constants (B,C,H,W) = (32,256,128,128), downsample 0.5 -> (64,64)
#define NB 32
#define NC 256
#define NH 128
#define NW 128
#define NDH 64
#define NDW 64
#define NHW (NH * NW)          // 16384
#define NCELLS (NDH * NDW)     // 4096
#define OUT0_N (NB * NC * NCELLS)       // out: 33,554,432 floats
#define OUT1_BASE OUT0_N
#define OUT1_N (NB * 2 * NHW)           // offset: 1,048,576 floats
#define OUT2_BASE (OUT1_BASE + OUT1_N)  // destination: 134,217,728 floats

#define EPSF 1e-5f

typedef unsigned short u16;
typedef unsigned int   u32;

// ---- workspace layout (bytes), 16B-aligned; total ~5.5 MB ----
#define WS_CELLS   ((size_t)0)                       // u16 [NB*NHW]   1 MB
#define WS_ATTS    (WS_CELLS + (size_t)NB*NHW*2)     // f32 [NB*NHW]   2 MB
#define WS_ECOMB   (WS_ATTS + (size_t)NB*NHW*4)      // u32 [NB*NHW]   2 MB  (cell<<16 | pix)
#define WS_ASUM    (WS_ECOMB + (size_t)NB*NHW*4)     // f32 [NB*NCELLS] 512 KB

__device__ __forceinline__ u16 f32_to_bf16_rn(float f) {
    const u32 u = __float_as_uint(f);
    return (u16)((u + 0x7FFFu + ((u >> 16) & 1u)) >> 16);
}

// ============================================================================
// K1: read-only conv stream. One block = 64 consecutive pixels of one image.
// Reads x once (coalesced float4); emits offset output + cells + atts.
// No destination write here (K3 does it as a pure write stream).
// ============================================================================
__global__ __launch_bounds__(256) void k_cells(
    const float* __restrict__ x, const float* __restrict__ cw,
    const float* __restrict__ cb, float* __restrict__ out,
    u16* __restrict__ cells, float* __restrict__ atts)
{
    __shared__ float cwS[3][NC];
    __shared__ float red[256][13];

    const int t    = threadIdx.x;
    const int blk  = blockIdx.x;
    const int b    = blk >> 8;
    const int tile = blk & 255;
    const int h    = tile >> 1;
    const int w0   = (tile & 1) << 6;
    const int pixbase = h * NW + w0;

    cwS[0][t] = cw[t];
    cwS[1][t] = cw[NC + t];
    cwS[2][t] = cw[2 * NC + t];
    __syncthreads();

    const int ct = t >> 4;            // channel group 0..15
    const int pg = (t & 15) << 2;     // pixel quad base 0..60
    const float* xb = x + (size_t)b * NC * NHW + pixbase + pg;

    float p00 = 0, p01 = 0, p02 = 0;
    float p10 = 0, p11 = 0, p12 = 0;
    float p20 = 0, p21 = 0, p22 = 0;
    float p30 = 0, p31 = 0, p32 = 0;

    #pragma unroll
    for (int i = 0; i < 16; ++i) {
        const int c = (i << 4) + ct;
        const float4 xv = *reinterpret_cast<const float4*>(xb + (size_t)c * NHW);
        const float wc0 = cwS[0][c], wc1 = cwS[1][c], wc2 = cwS[2][c];
        p00 += xv.x * wc0; p01 += xv.x * wc1; p02 += xv.x * wc2;
        p10 += xv.y * wc0; p11 += xv.y * wc1; p12 += xv.y * wc2;
        p20 += xv.z * wc0; p21 += xv.z * wc1; p22 += xv.z * wc2;
        p30 += xv.w * wc0; p31 += xv.w * wc1; p32 += xv.w * wc2;
    }

    red[t][0]  = p00; red[t][1]  = p01; red[t][2]  = p02;
    red[t][3]  = p10; red[t][4]  = p11; red[t][5]  = p12;
    red[t][6]  = p20; red[t][7]  = p21; red[t][8]  = p22;
    red[t][9]  = p30; red[t][10] = p31; red[t][11] = p32;
    __syncthreads();

    if (t < 64) {
        const int px   = t;
        const int row0 = px >> 2;
        const int col  = (px & 3) * 3;
        float s0 = 0, s1 = 0, s2 = 0;
        #pragma unroll
        for (int j = 0; j < 16; ++j) {
            const int r = row0 + (j << 4);
            s0 += red[r][col];
            s1 += red[r][col + 1];
            s2 += red[r][col + 2];
        }
        const float off0 = s0 + cb[0];
        const float off1 = s1 + cb[1];
        const float att  = expf(s2 + cb[2]);

        const float gy = (float)h * (1.0f / NH);
        const float gx = (float)(w0 + px) * (1.0f / NW);
        const float dyf = fminf(fmaxf(gy + off0, 0.0f), 0.99999f);
        const float dxf = fminf(fmaxf(gx + off1, 0.0f), 0.99999f);
        const int dy = (int)floorf(dyf * (float)NDH);
        const int dx = (int)floorf(dxf * (float)NDW);
        const int cell = dy * NDW + dx;

        cells[b * NHW + pixbase + px] = (u16)cell;
        atts [b * NHW + pixbase + px] = att;

        const int o1 = OUT1_BASE + b * 2 * NHW + pixbase + px;
        out[o1]       = off0;
        out[o1 + NHW] = off1;
    }
}

// ============================================================================
// K2: per-batch counting sort of pixels by cell, with WAVE-AGGREGATED atomics:
// equal-cell runs across consecutive lanes (common: clipped regions) are
// reduced with a segmented wave scan, so only run heads issue LDS atomics.
// Emits ecomb u32[NHW] = (cell<<16)|pix grouped by cell, and asum f32[4096].
// ============================================================================
__global__ __launch_bounds__(1024) void k_sort(
    const u16* __restrict__ cells, const float* __restrict__ atts,
    u32* __restrict__ ecomb, float* __restrict__ asum)
{
    __shared__ u32   hist[NCELLS];  // 16 KB
    __shared__ float as_[NCELLS];   // 16 KB
    __shared__ u32   ts[1024];      //  4 KB

    const int t    = threadIdx.x;
    const int b    = blockIdx.x;
    const int lane = t & 63;
    const u16*   cb_ = cells + b * NHW;
    const float* ab_ = atts + b * NHW;

    #pragma unroll
    for (int j = 0; j < 4; ++j) { hist[t + 1024 * j] = 0u; as_[t + 1024 * j] = 0.f; }
    __syncthreads();

    // Phase A: histogram + att-sum, one atomic pair per equal-cell run.
    #pragma unroll
    for (int j = 0; j < 16; ++j) {
        const int p  = t + 1024 * j;
        const int cl = cb_[p];
        const float av = ab_[p];

        const int clp = __shfl_up(cl, 1);
        const int cln = __shfl_down(cl, 1);
        const bool head = (lane == 0)  || (cl != clp);
        int  tl  = (lane == 63) ? 1 : (cl != cln ? 1 : 0);
        float s  = av;
        int   cnt = 1;
        #pragma unroll
        for (int d = 1; d < 64; d <<= 1) {
            const float s2 = __shfl_down(s, d);
            const int   c2 = __shfl_down(cnt, d);
            const int   t2 = __shfl_down(tl, d);
            if (!tl && lane + d < 64) { s += s2; cnt += c2; tl = t2; }
        }
        if (head) {
            atomicAdd(&hist[cl], (u32)cnt);
            atomicAdd(&as_[cl], s);
        }
    }
    __syncthreads();

    // Phase B: exclusive scan of hist[4096] (4/thread + Hillis-Steele on 1024)
    const u32 h0 = hist[4 * t], h1 = hist[4 * t + 1], h2 = hist[4 * t + 2], h3 = hist[4 * t + 3];
    const u32 T  = h0 + h1 + h2 + h3;
    ts[t] = T;
    __syncthreads();
    for (int off = 1; off < 1024; off <<= 1) {
        const u32 v = (t >= off) ? ts[t - off] : 0u;
        __syncthreads();
        ts[t] += v;
        __syncthreads();
    }
    const u32 base0 = ts[t] - T;
    hist[4 * t]     = base0;
    hist[4 * t + 1] = base0 + h0;
    hist[4 * t + 2] = base0 + h0 + h1;
    hist[4 * t + 3] = base0 + h0 + h1 + h2;

    #pragma unroll
    for (int j = 0; j < 4; ++j)
        asum[b * NCELLS + t + 1024 * j] = as_[t + 1024 * j];
    __syncthreads();

    // Phase C: scatter; run head does one cursor atomic, others offset from it.
    #pragma unroll
    for (int j = 0; j < 16; ++j) {
        const int p  = t + 1024 * j;
        const int cl = cb_[p];

        const int clp = __shfl_up(cl, 1);
        const int cln = __shfl_down(cl, 1);
        const bool head = (lane == 0)  || (cl != clp);
        int tl  = (lane == 63) ? 1 : (cl != cln ? 1 : 0);
        int cnt = 1;
        #pragma unroll
        for (int d = 1; d < 64; d <<= 1) {
            const int c2 = __shfl_down(cnt, d);
            const int t2 = __shfl_down(tl, d);
            if (!tl && lane + d < 64) { cnt += c2; tl = t2; }
        }
        int hl = head ? lane : 0;
        #pragma unroll
        for (int d = 1; d < 64; d <<= 1) {
            const int h2 = __shfl_up(hl, d);
            if (lane >= d) hl = max(hl, h2);
        }
        int base = 0;
        if (head) base = (int)atomicAdd(&hist[cl], (u32)cnt);
        base = __shfl(base, hl);
        const u32 pos = (u32)(base + (lane - hl));
        ecomb[b * NHW + pos] = ((u32)cl << 16) | (u32)p;
    }
}

// ============================================================================
// K3: pure write stream for the destination output.
// dest[b,c,pix] = float((b*C+c)*NCELLS + cell[pix]). cells is 1 MB (L3-hot).
// ============================================================================
__global__ __launch_bounds__(256) void k_dest(
    const u16* __restrict__ cells, float* __restrict__ out)
{
    __shared__ u16 cl_s[64];

    const int t    = threadIdx.x;
    const int blk  = blockIdx.x;
    const int b    = blk >> 8;
    const int tile = blk & 255;
    const int h    = tile >> 1;
    const int w0   = (tile & 1) << 6;
    const int pixbase = h * NW + w0;

    if (t < 64) cl_s[t] = cells[b * NHW + pixbase + t];
    __syncthreads();

    const int ct = t >> 4;
    const int pg = (t & 15) << 2;
    const int c0 = cl_s[pg], c1 = cl_s[pg + 1], c2 = cl_s[pg + 2], c3 = cl_s[pg + 3];

    float* __restrict__ dst = out + OUT2_BASE;
    #pragma unroll
    for (int i = 0; i < 16; ++i) {
        const int c = (i << 4) + ct;
        const int basec = (b * NC + c) * NCELLS;
        float4 dv;
        dv.x = (float)(basec + c0);
        dv.y = (float)(basec + c1);
        dv.z = (float)(basec + c2);
        dv.w = (float)(basec + c3);
        *reinterpret_cast<float4*>(dst + (size_t)(b * NC + c) * NHW + pixbase + pg) = dv;
    }
}

// ============================================================================
// K4: gather. One block per (b,c), 512 threads (8 waves; 48 KB LDS => 3
// blocks/CU => 24 waves/CU for HBM/LDS overlap). Stage bf16(x*att) into LDS;
// each thread consumes 32 sorted packed entries as TWO independent run-length
// streams of 16; rare LDS atomic flushes; coalesced normalized f32 write.
// ============================================================================
#define BF16V(E) __uint_as_float((u32)xpl[(E) & 0xFFFFu] << 16)
#define ACCUM(CUR, S, E, V)                                                   \
    {                                                                         \
        const int cl_ = (int)((E) >> 16);                                     \
        if (cl_ != (CUR)) { atomicAdd(&acc[(CUR)], (S)); (S) = 0.f; (CUR) = cl_; } \
        (S) += (V);                                                           \
    }

__global__ __launch_bounds__(512) void k_gather(
    const float* __restrict__ x, const float* __restrict__ atts,
    const u32* __restrict__ ecomb, const float* __restrict__ asum,
    float* __restrict__ out)
{
    __shared__ u16   xpl[NHW];     // 32 KB (bf16 x*att)
    __shared__ float acc[NCELLS];  // 16 KB

    const int t   = threadIdx.x;
    const int blk = blockIdx.x;
    const int b   = blk >> 8;
    const int c   = blk & 255;

    const float4* xp4  = reinterpret_cast<const float4*>(x + (size_t)(b * NC + c) * NHW);
    const float4* at4  = reinterpret_cast<const float4*>(atts + b * NHW);
    float4*       acc4 = reinterpret_cast<float4*>(acc);

    #pragma unroll
    for (int k = 0; k < 8; ++k) {
        const int idx = t + 512 * k;         // float4 index; pixels idx*4..+3
        const float4 xv = xp4[idx];
        const float4 av = at4[idx];
        const u32 lo = (u32)f32_to_bf16_rn(xv.x * av.x)
                     | ((u32)f32_to_bf16_rn(xv.y * av.y) << 16);
        const u32 hi = (u32)f32_to_bf16_rn(xv.z * av.z)
                     | ((u32)f32_to_bf16_rn(xv.w * av.w) << 16);
        *reinterpret_cast<uint2*>(&xpl[idx * 4]) = make_uint2(lo, hi);
    }
    const float4 z4 = make_float4(0.f, 0.f, 0.f, 0.f);
    #pragma unroll
    for (int k = 0; k < 2; ++k) acc4[t + 512 * k] = z4;
    __syncthreads();

    const u32* el = ecomb + b * NHW + t * 32;
    {
        float s0 = 0.f, s1 = 0.f;
        int   c0 = (int)(el[0]  >> 16);
        int   c1 = (int)(el[16] >> 16);
        #pragma unroll
        for (int ch = 0; ch < 4; ++ch) {
            const uint4 e0 = *reinterpret_cast<const uint4*>(el + ch * 4);
            const uint4 e1 = *reinterpret_cast<const uint4*>(el + 16 + ch * 4);
            const float v00 = BF16V(e0.x), v01 = BF16V(e0.y), v02 = BF16V(e0.z), v03 = BF16V(e0.w);
            const float v10 = BF16V(e1.x), v11 = BF16V(e1.y), v12 = BF16V(e1.z), v13 = BF16V(e1.w);
            ACCUM(c0, s0, e0.x, v00); ACCUM(c1, s1, e1.x, v10);
            ACCUM(c0, s0, e0.y, v01); ACCUM(c1, s1, e1.y, v11);
            ACCUM(c0, s0, e0.z, v02); ACCUM(c1, s1, e1.z, v12);
            ACCUM(c0, s0, e0.w, v03); ACCUM(c1, s1, e1.w, v13);
        }
        atomicAdd(&acc[c0], s0);
        atomicAdd(&acc[c1], s1);
    }
    __syncthreads();

    const float4* as4 = reinterpret_cast<const float4*>(asum + b * NCELLS);
    float4* ob4 = reinterpret_cast<float4*>(out + (size_t)(b * NC + c) * NCELLS);
    #pragma unroll
    for (int k = 0; k < 2; ++k) {
        float4 a = acc4[t + 512 * k];
        const float4 sv = as4[t + 512 * k];
        a.x /= (sv.x + EPSF);
        a.y /= (sv.y + EPSF);
        a.z /= (sv.z + EPSF);
        a.w /= (sv.w + EPSF);
        ob4[t + 512 * k] = a;
    }
}

extern "C" void kernel_launch(void* const* d_in, const int* in_sizes, int n_in,
                              void* d_out, int out_size, void* d_ws, size_t ws_size,
                              hipStream_t stream)
{
    (void)in_sizes; (void)n_in; (void)out_size; (void)ws_size;
    const float* x  = (const float*)d_in[0];
    const float* cw = (const float*)d_in[1];
    const float* cb = (const float*)d_in[2];
    float* out = (float*)d_out;
    char*  ws  = (char*)d_ws;

    u16*   cells = (u16*)  (ws + WS_CELLS);
    float* atts  = (float*)(ws + WS_ATTS);
    u32*   ecomb = (u32*)  (ws + WS_ECOMB);
    float* asum  = (float*)(ws + WS_ASUM);

    k_cells <<<dim3(NB * 256), dim3(256),  0, stream>>>(x, cw, cb, out, cells, atts);
    k_sort  <<<dim3(NB),       dim3(1024), 0, stream>>>(cells, atts, ecomb, asum);
    k_dest  <<<dim3(NB * 256), dim3(256),  0, stream>>>(cells, out);
    k_gather<<<dim3(NB * NC),  dim3(512),  0, stream>>>(x, atts, ecomb, asum, out);
}